// Round 1
// 730.889 us; speedup vs baseline: 1.1862x; 1.1862x over previous
//
#include <hip/hip_runtime.h>
#include <math.h>

typedef __attribute__((ext_vector_type(8))) short s16x8;
typedef __attribute__((ext_vector_type(4))) float f32x4;

__device__ __forceinline__ float b2f(unsigned short u){
  unsigned int i = ((unsigned int)u) << 16;
  float f; __builtin_memcpy(&f, &i, 4); return f;
}
__device__ __forceinline__ unsigned short f2b(float f){
  unsigned int i; __builtin_memcpy(&i, &f, 4);
  unsigned int r = (i + 0x7fffu + ((i >> 16) & 1u)) >> 16;
  return (unsigned short)r;
}
__device__ __forceinline__ f32x4 mfma16(s16x8 a, s16x8 b, f32x4 c){
  return __builtin_amdgcn_mfma_f32_16x16x32_bf16(a, b, c, 0, 0, 0);
}
__device__ __forceinline__ float gelu_exact(float x){
  return 0.5f * x * (1.0f + erff(x * 0.70710678118654752f));
}
// async global->LDS, 16 B per lane; lds base must be wave-uniform (m97 pattern)
__device__ __forceinline__ void gl_lds16(const unsigned short* g, unsigned short* l){
  __builtin_amdgcn_global_load_lds(
      (const __attribute__((address_space(1))) unsigned int*)g,
      (__attribute__((address_space(3))) unsigned int*)l, 16, 0, 0);
}

// ---------------- wave-per-row LayerNorm core (row of 1024, fp32 in, bf16 out) ----------------
__device__ __forceinline__ void ln_row(const float* __restrict__ xrow,
                                       const float* __restrict__ g,
                                       const float* __restrict__ b,
                                       unsigned short* __restrict__ orow, int lane){
  const float4* xr = (const float4*)xrow;
  float4 u[4];
  #pragma unroll
  for(int q = 0; q < 4; q++) u[q] = xr[lane + 64*q];
  float s = 0.0f, ss = 0.0f;
  #pragma unroll
  for(int q = 0; q < 4; q++){
    s  += u[q].x + u[q].y + u[q].z + u[q].w;
    ss += u[q].x*u[q].x + u[q].y*u[q].y + u[q].z*u[q].z + u[q].w*u[q].w;
  }
  #pragma unroll
  for(int o = 32; o; o >>= 1){ s += __shfl_xor(s, o, 64); ss += __shfl_xor(ss, o, 64); }
  float m = s * (1.0f/1024.0f);
  float inv = rsqrtf(ss * (1.0f/1024.0f) - m*m + 1e-5f);
  #pragma unroll
  for(int q = 0; q < 4; q++){
    float4 ug = ((const float4*)g)[lane + 64*q];
    float4 ub = ((const float4*)b)[lane + 64*q];
    ushort4 o4;
    o4.x = f2b((u[q].x - m) * inv * ug.x + ub.x);
    o4.y = f2b((u[q].y - m) * inv * ug.y + ub.y);
    o4.z = f2b((u[q].z - m) * inv * ug.z + ub.z);
    o4.w = f2b((u[q].w - m) * inv * ug.w + ub.w);
    ((ushort4*)orow)[lane + 64*q] = o4;
  }
}

// ---------------- prep: 6 weight transposes (fp32 -> bf16) + LN1, one dispatch ----------------
// blocks [0,10240): transposes; [10240,14336): LN1 (4 rows/block, wave per row)
__global__ __launch_bounds__(256) void prep_k(
    const float* __restrict__ x, const float* __restrict__ ln1_g, const float* __restrict__ ln1_b,
    unsigned short* __restrict__ h,
    const float* __restrict__ wq, const float* __restrict__ wk, const float* __restrict__ wv,
    const float* __restrict__ wo, const float* __restrict__ wff1, const float* __restrict__ wff2,
    unsigned short* __restrict__ wqkvT, unsigned short* __restrict__ woT,
    unsigned short* __restrict__ wff1T, unsigned short* __restrict__ wff2T)
{
  const int bz = blockIdx.x;
  if(bz >= 10240){
    int id = bz - 10240;
    int lane = threadIdx.x & 63, wave = threadIdx.x >> 6;
    int row = id * 4 + wave;
    ln_row(x + (size_t)row*1024, ln1_g, ln1_b, h + (size_t)row*1024, lane);
    return;
  }
  const float* in; unsigned short* out; int R, C, c0, r0;
  if(bz < 4096){
    int w = bz >> 10, id = bz & 1023;       // 4 square 1024x1024 weights
    const float* srcs[4] = {wq, wk, wv, wo};
    unsigned short* dsts[4] = {wqkvT, wqkvT + 1048576, wqkvT + 2097152, woT};
    in = srcs[w]; out = dsts[w]; R = 1024; C = 1024;
    c0 = (id & 31) * 32; r0 = (id >> 5) * 32;
  } else if(bz < 8192){
    int id = bz - 4096;                     // wff1: 1024x4096, grid 128x32
    in = wff1; out = wff1T; R = 1024; C = 4096;
    c0 = (id & 127) * 32; r0 = (id >> 7) * 32;
  } else {
    int id = bz - 8192;                     // wff2: 2048x1024, grid 32x64
    in = wff2; out = wff2T; R = 2048; C = 1024;
    c0 = (id & 31) * 32; r0 = (id >> 5) * 32;
  }
  __shared__ unsigned short tile[32][33];
  int tx = threadIdx.x & 31, ty = threadIdx.x >> 5;   // 32x8
  #pragma unroll
  for(int i = 0; i < 4; i++)
    tile[ty + 8*i][tx] = f2b(in[(size_t)(r0 + ty + 8*i) * C + c0 + tx]);
  __syncthreads();
  #pragma unroll
  for(int i = 0; i < 4; i++)
    out[(size_t)(c0 + ty + 8*i) * R + r0 + tx] = tile[tx][ty + 8*i];
}

// ---------------- standalone LN2 (fp32 in, bf16 out), 4 rows/block ----------------
__global__ __launch_bounds__(256) void ln2_k(const float* __restrict__ x,
                                             const float* __restrict__ g,
                                             const float* __restrict__ b,
                                             unsigned short* __restrict__ out){
  int lane = threadIdx.x & 63, wave = threadIdx.x >> 6;
  int row = blockIdx.x * 4 + wave;
  ln_row(x + (size_t)row*1024, g, b, out + (size_t)row*1024, lane);
}

// ---------------- 256x256-tile, 8-wave, 4-phase pipelined GEMM (T3+T4+T5) ----------------
// Double-buffered 128 KiB LDS. Per K-tile (BK=64): 4 phases x 16 MFMA/wave; tile t+1's
// four half-tiles staged across tile t's phases via global_load_lds; ONE counted
// s_waitcnt vmcnt(2) per K-tile (never a drain-to-0 in steady state); 2 barriers/K-tile.
// MODE 0: bf16 out, column-split  (Cv stride n_split | Cv2 stride N-n_split)
// MODE 1: GEGLU FF1. Bt rows [0,2048)=val, [2048,4096)=gate; B-tile interleaves
//         val/gate in 16-col groups so each lane holds matching (row,col) val+gate
//         accumulators -> in-register  out = (val+bv) * gelu(gate+bg). C stride 2048.
// MODE 2: fp32 out = acc + bias[col] + res[row*N+col], stride N.
template<int MODE>
__global__ __launch_bounds__(512, 1) void gemm256(
    const unsigned short* __restrict__ A, const unsigned short* __restrict__ Bt,
    void* Cv, void* Cv2, int N, int n_split, int K,
    const float* __restrict__ bias, const float* __restrict__ res)
{
  __shared__ __align__(16) unsigned short As[2][256*64];
  __shared__ __align__(16) unsigned short Bs[2][256*64];

  int m_tile, n_tile;
  {
    unsigned int lin = blockIdx.y * gridDim.x + blockIdx.x;
    unsigned int mpx = gridDim.y >> 3;          // m-tiles per XCD (64/8 = 8)
    unsigned int xcd = lin & 7u, idx = lin >> 3;
    m_tile = xcd * mpx + (idx % mpx);
    n_tile = idx / mpx;
  }
  const int m0 = m_tile * 256;
  const int n0 = n_tile * (MODE == 1 ? 128 : 256);
  const int tid = threadIdx.x;
  const int wave = tid >> 6, lane = tid & 63;
  const int ln3 = lane >> 3;
  const int cg  = (lane & 7) ^ ln3;             // XOR-swizzled col-group (write side)
  const int wm = (wave >> 2) * 128, wn = (wave & 3) * 64;
  const int lrow = lane & 15, quad = lane >> 4, xw = lrow & 7;

  // staging source pointers: (h,q) -> hq = h*2+q, row = hq*64 + wave*8 + ln3
  const unsigned short* aSrc[4];
  const unsigned short* bSrc[4];
  #pragma unroll
  for(int hq = 0; hq < 4; hq++){
    int rt = hq*64 + wave*8 + ln3;
    aSrc[hq] = A + (size_t)(m0 + rt)*K + cg*8;
    int brow;
    if(MODE == 1){
      int grp = rt >> 4;                        // 16-row group: even=val, odd=gate
      brow = (grp & 1)*2048 + n0 + ((grp >> 1)*16) + (rt & 15);
    } else {
      brow = n0 + rt;
    }
    bSrc[hq] = Bt + (size_t)brow*K + cg*8;
  }

#define STAGE_A(bsel, hh, koff) do{ \
    gl_lds16(aSrc[(hh)*2+0] + (koff), &As[(bsel)][(hh)*8192 + wave*512]); \
    gl_lds16(aSrc[(hh)*2+1] + (koff), &As[(bsel)][(hh)*8192 + 4096 + wave*512]); }while(0)
#define STAGE_B(bsel, hh, koff) do{ \
    gl_lds16(bSrc[(hh)*2+0] + (koff), &Bs[(bsel)][(hh)*8192 + wave*512]); \
    gl_lds16(bSrc[(hh)*2+1] + (koff), &Bs[(bsel)][(hh)*8192 + 4096 + wave*512]); }while(0)
#define RD(buf, rowbase, kk) \
    (*(const s16x8*)&(buf)[((rowbase) + lrow)*64 + (((((kk)<<2)+quad)^xw)*8)])

  f32x4 acc[8][4];
  #pragma unroll
  for(int i = 0; i < 8; i++)
    #pragma unroll
    for(int j = 0; j < 4; j++)
      #pragma unroll
      for(int r = 0; r < 4; r++) acc[i][j][r] = 0.0f;

  // prologue: stage K-tile 0 into buffer 0 (8 gl_lds16 / thread)
  STAGE_A(0,0,0); STAGE_A(0,1,0); STAGE_B(0,0,0); STAGE_B(0,1,0);

  s16x8 af[4][2], bf[4][2];
  const int nk = K >> 6;
  #pragma unroll 2
  for(int kt = 0; kt < nk; kt++){
    const int cur = kt & 1, nxt = cur ^ 1;
    const int koff = (kt + 1) << 6;             // shorts along K for tile kt+1
    const bool pf = (kt + 1 < nk);

    // ---- phase 0: stage A-h0(t+1); drain tile-t stages (keep 2 newest in flight)
    if(pf){ STAGE_A(nxt, 0, koff);
            asm volatile("s_waitcnt vmcnt(2)\n\ts_barrier" ::: "memory"); }
    else  { asm volatile("s_waitcnt vmcnt(0)\n\ts_barrier" ::: "memory"); }
    #pragma unroll
    for(int i = 0; i < 4; i++){ af[i][0] = RD(As[cur], wm + i*16, 0);
                                af[i][1] = RD(As[cur], wm + i*16, 1); }
    #pragma unroll
    for(int j = 0; j < 2; j++){ bf[j][0] = RD(Bs[cur], wn + j*16, 0);
                                bf[j][1] = RD(Bs[cur], wn + j*16, 1); }
    __builtin_amdgcn_s_setprio(1);
    #pragma unroll
    for(int i = 0; i < 4; i++)
      #pragma unroll
      for(int j = 0; j < 2; j++){
        acc[i][j] = mfma16(af[i][0], bf[j][0], acc[i][j]);
        acc[i][j] = mfma16(af[i][1], bf[j][1], acc[i][j]);
      }
    __builtin_amdgcn_s_setprio(0);

    // ---- phase 1: stage A-h1(t+1)
    if(pf) STAGE_A(nxt, 1, koff);
    #pragma unroll
    for(int j = 2; j < 4; j++){ bf[j][0] = RD(Bs[cur], wn + j*16, 0);
                                bf[j][1] = RD(Bs[cur], wn + j*16, 1); }
    __builtin_amdgcn_s_setprio(1);
    #pragma unroll
    for(int i = 0; i < 4; i++)
      #pragma unroll
      for(int j = 2; j < 4; j++){
        acc[i][j] = mfma16(af[i][0], bf[j][0], acc[i][j]);
        acc[i][j] = mfma16(af[i][1], bf[j][1], acc[i][j]);
      }
    __builtin_amdgcn_s_setprio(0);

    // ---- phase 2: stage B-h0(t+1); switch to A rows wm+64..wm+127
    if(pf) STAGE_B(nxt, 0, koff);
    #pragma unroll
    for(int i = 0; i < 4; i++){ af[i][0] = RD(As[cur], wm + 64 + i*16, 0);
                                af[i][1] = RD(As[cur], wm + 64 + i*16, 1); }
    __builtin_amdgcn_s_setprio(1);
    #pragma unroll
    for(int i = 0; i < 4; i++)
      #pragma unroll
      for(int j = 0; j < 2; j++){
        acc[4+i][j] = mfma16(af[i][0], bf[j][0], acc[4+i][j]);
        acc[4+i][j] = mfma16(af[i][1], bf[j][1], acc[4+i][j]);
      }
    __builtin_amdgcn_s_setprio(0);

    // ---- phase 3: stage B-h1(t+1)
    if(pf) STAGE_B(nxt, 1, koff);
    __builtin_amdgcn_s_setprio(1);
    #pragma unroll
    for(int i = 0; i < 4; i++)
      #pragma unroll
      for(int j = 2; j < 4; j++){
        acc[4+i][j] = mfma16(af[i][0], bf[j][0], acc[4+i][j]);
        acc[4+i][j] = mfma16(af[i][1], bf[j][1], acc[4+i][j]);
      }
    __builtin_amdgcn_s_setprio(0);
    // end of tile: this wave's LDS reads of buf[cur] must be complete before any
    // wave can start re-staging buf[cur] (next iteration's phase 0)
    asm volatile("s_waitcnt lgkmcnt(0)\n\ts_barrier" ::: "memory");
  }
#undef STAGE_A
#undef STAGE_B
#undef RD

  const int qr = quad * 4;
  if(MODE == 1){
    unsigned short* C = (unsigned short*)Cv;
    const int a4 = wave & 3;
    #pragma unroll
    for(int i = 0; i < 8; i++){
      #pragma unroll
      for(int gp = 0; gp < 2; gp++){
        int colv = n0 + a4*32 + gp*16 + lrow;
        float bv = bias[colv];
        float bg = bias[2048 + colv];
        #pragma unroll
        for(int r = 0; r < 4; r++){
          size_t row = (size_t)(m0 + wm + i*16 + qr + r);
          float v  = acc[i][2*gp  ][r] + bv;
          float gt = acc[i][2*gp+1][r] + bg;
          C[row*2048 + colv] = f2b(v * gelu_exact(gt));
        }
      }
    }
  } else if(MODE == 0){
    unsigned short* C1 = (unsigned short*)Cv;
    unsigned short* C2 = (unsigned short*)Cv2;
    #pragma unroll
    for(int i = 0; i < 8; i++)
      #pragma unroll
      for(int j = 0; j < 4; j++){
        int col = n0 + wn + j*16 + lrow;
        #pragma unroll
        for(int r = 0; r < 4; r++){
          size_t row = (size_t)(m0 + wm + i*16 + qr + r);
          if(col < n_split) C1[row*n_split + col] = f2b(acc[i][j][r]);
          else              C2[row*(N - n_split) + (col - n_split)] = f2b(acc[i][j][r]);
        }
      }
  } else {
    float* C = (float*)Cv;
    #pragma unroll
    for(int i = 0; i < 8; i++)
      #pragma unroll
      for(int j = 0; j < 4; j++){
        int col = n0 + wn + j*16 + lrow;
        float bv = bias[col];
        #pragma unroll
        for(int r = 0; r < 4; r++){
          size_t row = (size_t)(m0 + wm + i*16 + qr + r);
          size_t idx = row * (size_t)N + col;
          C[idx] = acc[i][j][r] + bv + res[idx];
        }
      }
  }
}

// ---------------- sliding-window local attention ----------------
__global__ __launch_bounds__(256, 1) void attn_k(const unsigned short* __restrict__ qk,
                                                 const unsigned short* __restrict__ vbuf,
                                                 const float* __restrict__ rel_bias,
                                                 unsigned short* __restrict__ attn_out)
{
  __shared__ unsigned short kvS[128 * 72];
  __shared__ unsigned short PS[128 * 136];
  __shared__ float biasS[256];

  const int n = blockIdx.x, h = blockIdx.y, b = blockIdx.z;
  const int tid = threadIdx.x;
  const int wave = tid >> 6, lane = tid & 63;
  const int lrow = lane & 15, quad = lane >> 4, lk = quad * 8;
  const int rbase = wave * 32;
  const size_t rowbase = (size_t)b * 4096;
  const int prev = (n > 0) ? (n - 1) : 0;

  biasS[tid] = rel_bias[h * 256 + tid];

  s16x8 aq[2][2];
  #pragma unroll
  for(int mi = 0; mi < 2; mi++)
    #pragma unroll
    for(int kk = 0; kk < 2; kk++)
      aq[mi][kk] = *(const s16x8*)&qk[(rowbase + n*128 + rbase + mi*16 + lrow)*2048
                                      + h*64 + kk*32 + lk];

  f32x4 lg[2][16];
  #pragma unroll
  for(int mi = 0; mi < 2; mi++)
    #pragma unroll
    for(int nj = 0; nj < 16; nj++)
      #pragma unroll
      for(int r = 0; r < 4; r++) lg[mi][nj][r] = 0.0f;

  for(int jh = 0; jh < 2; jh++){
    if(jh) __syncthreads();
    #pragma unroll
    for(int it = 0; it < 4; it++){
      int cid = tid + it * 256;
      int jloc = cid >> 3, c8 = (cid & 7) * 8;
      int j = jh * 128 + jloc;
      int srow = (j < 128) ? (prev*128 + j) : (n*128 + j - 128);
      *(s16x8*)&kvS[jloc*72 + c8] =
        *(const s16x8*)&qk[(rowbase + srow)*2048 + 1024 + h*64 + c8];
    }
    __syncthreads();
    #pragma unroll
    for(int njl = 0; njl < 8; njl++){
      #pragma unroll
      for(int kk = 0; kk < 2; kk++){
        s16x8 bk = *(const s16x8*)&kvS[(njl*16 + lrow)*72 + kk*32 + lk];
        #pragma unroll
        for(int mi = 0; mi < 2; mi++)
          lg[mi][jh*8 + njl] = mfma16(aq[mi][kk], bk, lg[mi][jh*8 + njl]);
      }
    }
  }
  __syncthreads();

  #pragma unroll
  for(int mi = 0; mi < 2; mi++){
    #pragma unroll
    for(int r = 0; r < 4; r++){
      int i = rbase + mi*16 + quad*4 + r;
      float mx = -3e38f;
      #pragma unroll
      for(int nj = 0; nj < 16; nj++){
        int j = nj*16 + lrow;
        int dist = i + 128 - j;
        bool valid = (dist >= 0) && ((n > 0) || (j >= 128));
        float l = valid ? (lg[mi][nj][r] * 0.125f + biasS[dist & 255]) : -1e9f;
        lg[mi][nj][r] = l;
        mx = fmaxf(mx, l);
      }
      #pragma unroll
      for(int o = 1; o < 16; o <<= 1) mx = fmaxf(mx, __shfl_xor(mx, o, 64));
      float s = 0.0f;
      #pragma unroll
      for(int nj = 0; nj < 16; nj++){
        float p = __expf(lg[mi][nj][r] - mx);
        lg[mi][nj][r] = p;
        s += p;
      }
      #pragma unroll
      for(int o = 1; o < 16; o <<= 1) s += __shfl_xor(s, o, 64);
      float inv = 1.0f / s;
      #pragma unroll
      for(int nj = 0; nj < 16; nj++) lg[mi][nj][r] *= inv;
    }
  }

  f32x4 o_acc[2][4];
  #pragma unroll
  for(int mi = 0; mi < 2; mi++)
    #pragma unroll
    for(int nj = 0; nj < 4; nj++)
      #pragma unroll
      for(int r = 0; r < 4; r++) o_acc[mi][nj][r] = 0.0f;

  for(int jh = 0; jh < 2; jh++){
    {
      int jloc = tid >> 1;
      int dbase = (tid & 1) * 32;
      int j = jh * 128 + jloc;
      int srow = (j < 128) ? (prev*128 + j) : (n*128 + j - 128);
      const unsigned short* vr = &vbuf[(rowbase + srow)*1024 + h*64 + dbase];
      #pragma unroll
      for(int i8 = 0; i8 < 4; i8++){
        s16x8 vv = *(const s16x8*)&vr[i8 * 8];
        #pragma unroll
        for(int e = 0; e < 8; e++)
          kvS[(dbase + i8*8 + e)*136 + jloc] = (unsigned short)vv[e];
      }
    }
    #pragma unroll
    for(int mi = 0; mi < 2; mi++)
      #pragma unroll
      for(int r = 0; r < 4; r++)
        #pragma unroll
        for(int njl = 0; njl < 8; njl++)
          PS[(rbase + mi*16 + quad*4 + r)*136 + njl*16 + lrow] = f2b(lg[mi][jh*8 + njl][r]);
    __syncthreads();
    #pragma unroll
    for(int kk = 0; kk < 4; kk++){
      s16x8 ap[2];
      #pragma unroll
      for(int mi = 0; mi < 2; mi++)
        ap[mi] = *(const s16x8*)&PS[(rbase + mi*16 + lrow)*136 + kk*32 + lk];
      #pragma unroll
      for(int nj = 0; nj < 4; nj++){
        s16x8 bv = *(const s16x8*)&kvS[(nj*16 + lrow)*136 + kk*32 + lk];
        #pragma unroll
        for(int mi = 0; mi < 2; mi++)
          o_acc[mi][nj] = mfma16(ap[mi], bv, o_acc[mi][nj]);
      }
    }
    __syncthreads();
  }

  #pragma unroll
  for(int mi = 0; mi < 2; mi++)
    #pragma unroll
    for(int nj = 0; nj < 4; nj++)
      #pragma unroll
      for(int r = 0; r < 4; r++){
        size_t row = rowbase + n*128 + rbase + mi*16 + quad*4 + r;
        int col = h*64 + nj*16 + lrow;
        attn_out[row * 1024 + col] = f2b(o_acc[mi][nj][r]);
      }
}

// ---------------- launcher ----------------
extern "C" void kernel_launch(void* const* d_in, const int* in_sizes, int n_in,
                              void* d_out, int out_size, void* d_ws, size_t ws_size,
                              hipStream_t stream) {
  const float* x     = (const float*)d_in[0];
  const float* ln1_g = (const float*)d_in[1];
  const float* ln1_b = (const float*)d_in[2];
  const float* ln2_g = (const float*)d_in[3];
  const float* ln2_b = (const float*)d_in[4];
  const float* wq    = (const float*)d_in[5];
  const float* wk    = (const float*)d_in[6];
  const float* wv    = (const float*)d_in[7];
  const float* wo    = (const float*)d_in[8];
  const float* bo    = (const float*)d_in[9];
  const float* rel   = (const float*)d_in[10];
  const float* wff1  = (const float*)d_in[11];
  const float* bff1  = (const float*)d_in[12];
  const float* wff2  = (const float*)d_in[13];
  const float* bff2  = (const float*)d_in[14];
  float* out = (float*)d_out;
  char*  ws  = (char*)d_ws;

  // ws layout (byte offsets). Peak usage: 118.6 MiB.
  unsigned short* wqkvT = (unsigned short*)(ws);              //  6 MB
  unsigned short* woT   = (unsigned short*)(ws +  6291456);   //  2 MB
  unsigned short* wff1T = (unsigned short*)(ws +  8388608);   //  8 MB
  unsigned short* wff2T = (unsigned short*)(ws + 16777216);   //  4 MB
  unsigned short* h     = (unsigned short*)(ws + 20971520);   // 32 MB (ln1/attn_out/ln2)
  unsigned short* qk    = (unsigned short*)(ws + 54525952);   // 64 MB ([q|k] stride 2048)
  unsigned short* ff    = qk;                                 // geglu out reuses dead qk
  unsigned short* vbuf  = (unsigned short*)d_out;             // V bf16 scratch (dead until x1)
  float*          x1    = out;                                // fp32, in d_out

  // 1) transposes + LN1
  prep_k<<<14336, 256, 0, stream>>>(x, ln1_g, ln1_b, h,
                                    wq, wk, wv, wo, wff1, wff2,
                                    wqkvT, woT, wff1T, wff2T);
  // 2) [qk | v] = h @ [wq|wk|wv]   (256-tile pipelined core, split epilogue)
  gemm256<0><<<dim3(12, 64), 512, 0, stream>>>(h, wqkvT, qk, vbuf, 3072, 2048, 1024,
                                               nullptr, nullptr);
  // 3) attention -> h
  attn_k<<<dim3(32, 16, 4), 256, 0, stream>>>(qk, vbuf, rel, h);
  // 4) x1 = x + attn_out @ wo + bo  (fp32 into d_out)
  gemm256<2><<<dim3(4, 64), 512, 0, stream>>>(h, woT, x1, nullptr, 1024, 0, 1024,
                                              bo, x);
  // 5) h = bf16(LN2(x1))
  ln2_k<<<4096, 256, 0, stream>>>(x1, ln2_g, ln2_b, h);
  // 6) ff = (h@Wv + bv) * gelu(h@Wg + bg)   (GEGLU, val/gate interleaved in-register)
  gemm256<1><<<dim3(16, 64), 512, 0, stream>>>(h, wff1T, ff, nullptr, 2048, 0, 1024,
                                               bff1, nullptr);
  // 7) out = x1 + ff @ w_ff2 + b_ff2  (fp32, same-thread RMW on d_out)
  gemm256<2><<<dim3(4, 64), 512, 0, stream>>>(ff, wff2T, out, nullptr, 1024, 0, 2048,
                                              bff2, x1);
}